// Round 7
// baseline (356.707 us; speedup 1.0000x reference)
//
#include <hip/hip_runtime.h>
#include <hip/hip_bf16.h>
#include <math.h>

// Dtype model (pinned R0-R4): float inputs arrive f32; edge_index int32;
// d_out read as f32: chunk0 = pred f32[0:393216], chunk1 = yg f32[393216:786432];
// np reference computed from bf16-cast inputs -> bf16 intermediates are safe
// (R5/R6 passed at absmax 6.1e-5 vs threshold 9.25e-2).

#define N_NODES 16384
#define B_GRAPHS 256
#define K_NODES 64
#define DEG 8
#define NHEADS 4
#define C1 100
#define C2 128
#define IN_F 96
#define HID 64
#define OUT_SZ 24
#define PRED_ELEMS (K_NODES * B_GRAPHS * OUT_SZ)   // 393216

using bf16 = __hip_bfloat16;
typedef __attribute__((ext_vector_type(8))) short          frag_ab;  // 8 bf16
typedef __attribute__((ext_vector_type(4))) float          frag_cd;  // 4 f32
typedef unsigned short us8 __attribute__((ext_vector_type(8)));      // 16 B

__device__ __forceinline__ float ldf(const float* p) { return *p; }
__device__ __forceinline__ float ldf(const bf16* p) { return __bfloat162float(*p); }
__device__ __forceinline__ float us2f(unsigned short u) {
  return __bfloat162float(__ushort_as_bfloat16(u));
}
__device__ __forceinline__ short f2bf_s(float f) {
  return __builtin_bit_cast(short, __float2bfloat16(f));
}

// ---------------------------------------------------------------------------
// MFMA GEMM (unchanged from R6, verified): A [M,KDIM] (f32 or bf16-as-ushort)
// @ B [KDIM,NDIM] (f32) -> C bf16. BM=128 x BN=64, full K in LDS.
// ---------------------------------------------------------------------------
template<int KDIM, int KP, int NDIM, typename AT>
__global__ __launch_bounds__(256)
void gemm_mfma(const AT* __restrict__ A, const float* __restrict__ B,
               bf16* __restrict__ C) {
  constexpr int BM = 128, BN = 64;
  constexpr int LDA = KP + 8;
  constexpr int LDB = KP + 8;
  __shared__ __align__(16) short As[BM * LDA];
  __shared__ __align__(16) short Bs[BN * LDB];
  const int t  = threadIdx.x;
  const int m0 = blockIdx.y * BM;
  const int n0 = blockIdx.x * BN;

  if constexpr (sizeof(AT) == 4) {
    constexpr int QR = KDIM / 4;
    for (int idx = t; idx < BM * QR; idx += 256) {
      int m = idx / QR, q = idx - m * QR;
      const float4 v = *(const float4*)((const float*)A + (size_t)(m0 + m) * KDIM + q * 4);
      short* d = &As[m * LDA + q * 4];
      d[0] = f2bf_s(v.x); d[1] = f2bf_s(v.y); d[2] = f2bf_s(v.z); d[3] = f2bf_s(v.w);
    }
  } else {
    constexpr int PR = KDIM / 2;
    for (int idx = t; idx < BM * PR; idx += 256) {
      int m = idx / PR, p = idx - m * PR;
      const ushort2 v = *(const ushort2*)((const unsigned short*)A +
                                          (size_t)(m0 + m) * KDIM + p * 2);
      As[m * LDA + p * 2]     = (short)v.x;
      As[m * LDA + p * 2 + 1] = (short)v.y;
    }
    if constexpr (KP > KDIM) {
      constexpr int TR = KP - KDIM;
      for (int idx = t; idx < BM * TR; idx += 256) {
        int m = idx / TR, k = idx - m * TR;
        As[m * LDA + KDIM + k] = 0;
      }
    }
  }

  for (int idx = t; idx < KDIM * BN; idx += 256) {
    int k = idx >> 6, n = idx & 63;
    int gn = n0 + n;
    float v = (gn < NDIM) ? B[(size_t)k * NDIM + gn] : 0.f;
    Bs[n * LDB + k] = f2bf_s(v);
  }
  if constexpr (KP > KDIM) {
    constexpr int TR = KP - KDIM;
    for (int idx = t; idx < BN * TR; idx += 256) {
      int n = idx / TR, k = KDIM + (idx - n * TR);
      Bs[n * LDB + k] = 0;
    }
  }
  __syncthreads();

  const int wv = t >> 6;
  const int l  = t & 63;
  const int lm = l & 15;
  const int lk = (l >> 4) * 8;
  const int mw = wv * 32;

  frag_cd acc[2][4] = {};
#pragma unroll
  for (int ks = 0; ks < KP; ks += 32) {
    frag_ab a[2], b[4];
#pragma unroll
    for (int mt = 0; mt < 2; ++mt)
      a[mt] = *(const frag_ab*)&As[(mw + mt * 16 + lm) * LDA + ks + lk];
#pragma unroll
    for (int nt = 0; nt < 4; ++nt)
      b[nt] = *(const frag_ab*)&Bs[(nt * 16 + lm) * LDB + ks + lk];
#pragma unroll
    for (int mt = 0; mt < 2; ++mt)
#pragma unroll
      for (int nt = 0; nt < 4; ++nt)
        acc[mt][nt] = __builtin_amdgcn_mfma_f32_16x16x32_bf16(
            a[mt], b[nt], acc[mt][nt], 0, 0, 0);
  }

  const int rq = (l >> 4) * 4;
#pragma unroll
  for (int mt = 0; mt < 2; ++mt) {
#pragma unroll
    for (int nt = 0; nt < 4; ++nt) {
      int gn = n0 + nt * 16 + lm;
      if (gn < NDIM) {
#pragma unroll
        for (int r = 0; r < 4; ++r) {
          int gm = m0 + mw + mt * 16 + rq + r;
          C[(size_t)gm * NDIM + gn] = __float2bfloat16(acc[mt][nt][r]);
        }
      }
    }
  }
}

// ---------------------------------------------------------------------------
// Fused per-graph attention: one block per graph (grid=256=CU count).
// Stages the graph's xl slab (64 x 4C bf16) in LDS, then computes attention
// logits (als/ald), per-edge softmax (8 edges + self-loop), and the weighted
// aggregation + head-mean + bias (+ELU) entirely from LDS.
// ---------------------------------------------------------------------------
template<int C, bool ELU>
__global__ __launch_bounds__(256)
void att_fused(const bf16* __restrict__ xl, const int* __restrict__ esrc,
               const float* __restrict__ a_src, const float* __restrict__ a_dst,
               const float* __restrict__ bias, bf16* __restrict__ out) {
  constexpr int C4  = NHEADS * C;     // 400 / 512
  constexpr int LDX = C4 + 8;         // shorts; 816B/1040B row stride, 16B-aligned
  __shared__ __align__(16) unsigned short xs[K_NODES * LDX];
  __shared__ float avs[C4], avd[C4];
  __shared__ float bia[C];
  __shared__ int   edg[K_NODES * DEG];          // local src ids
  __shared__ float als[K_NODES][NHEADS], ald[K_NODES][NHEADS];
  __shared__ float w[K_NODES][NHEADS * 9];

  const int g = blockIdx.x;
  const int t = threadIdx.x;

  // ---- phase 1: stage slab + params ----
  const unsigned short* slab = (const unsigned short*)xl + (size_t)g * K_NODES * C4;
  constexpr int CPR = C4 / 8;                    // 16B chunks per row (50 / 64)
  for (int cidx = t; cidx < K_NODES * CPR; cidx += 256) {
    int r = cidx / CPR, o = cidx - r * CPR;
    *(us8*)&xs[r * LDX + o * 8] = *(const us8*)(slab + (size_t)cidx * 8);
  }
  for (int idx = t; idx < C4; idx += 256) {
    avs[idx] = a_src[idx];
    avd[idx] = a_dst[idx];
  }
  if (t < C) bia[t] = bias[t];
  for (int idx = t; idx < K_NODES * DEG; idx += 256)
    edg[idx] = esrc[g * K_NODES * DEG + idx] & (K_NODES - 1);  // graph-local id
  __syncthreads();

  // ---- phase 2: attention logits (thread = (node, head)) ----
  {
    const int n = t >> 2, h = t & 3;
    const unsigned short* row = &xs[n * LDX + h * C];
    const float* pas = &avs[h * C];
    const float* pad = &avd[h * C];
    float ss = 0.f, sd = 0.f;
    for (int c = 0; c < C; ++c) {
      float v = us2f(row[c]);
      ss += v * pas[c];
      sd += v * pad[c];
    }
    als[n][h] = ss;
    ald[n][h] = sd;
  }
  __syncthreads();

  // ---- phase 3: softmax over 9 incoming edges (thread = (node, head)) ----
  {
    const int n = t >> 2, h = t & 3;
    float a[9];
    const float ad = ald[n][h];
#pragma unroll
    for (int j = 0; j < 8; ++j) {
      float v = als[edg[n * DEG + j]][h] + ad;
      a[j] = (v >= 0.f) ? v : 0.2f * v;
    }
    {
      float v = als[n][h] + ad;
      a[8] = (v >= 0.f) ? v : 0.2f * v;
    }
    float m = -1e30f;
#pragma unroll
    for (int j = 0; j < 9; ++j) m = fmaxf(m, a[j]);
    float s = 0.f;
#pragma unroll
    for (int j = 0; j < 9; ++j) { a[j] = __expf(a[j] - m); s += a[j]; }
    float inv = 1.f / (s + 1e-16f);
#pragma unroll
    for (int j = 0; j < 9; ++j) w[n][h * 9 + j] = a[j] * inv;
  }
  __syncthreads();

  // ---- phase 4: weighted aggregation + head mean + bias (+ELU) ----
  for (int idx = t; idx < K_NODES * C; idx += 256) {
    const int n = idx / C, c = idx - n * C;
    int s[9];
#pragma unroll
    for (int j = 0; j < 8; ++j) s[j] = edg[n * DEG + j];
    s[8] = n;
    float acc = 0.f;
#pragma unroll
    for (int h = 0; h < NHEADS; ++h) {
      const float* wn = &w[n][h * 9];
      float hacc = 0.f;
#pragma unroll
      for (int j = 0; j < 9; ++j)
        hacc += wn[j] * us2f(xs[s[j] * LDX + h * C + c]);
      acc += hacc;
    }
    acc = acc * 0.25f + bia[c];
    if (ELU) acc = (acc > 0.f) ? acc : (__expf(acc) - 1.f);
    out[((size_t)g * K_NODES + n) * C + c] = __float2bfloat16(acc);
  }
}

// ---------------------------------------------------------------------------
// Per-node-index MLP head. Block k, thread b. x row gathered via 16B loads.
// pred[k,b,:] = relu(h2[b*64+k,:] @ fw1[k] + fb1[k]) @ fw2[k] + fb2[k]  (f32)
// ---------------------------------------------------------------------------
__global__ __launch_bounds__(256)
void mlp_kernel(const bf16* __restrict__ h2,
                const float* __restrict__ fw1, const float* __restrict__ fb1,
                const float* __restrict__ fw2, const float* __restrict__ fb2,
                float* __restrict__ pred) {
  const int k = blockIdx.x;
  const int b = threadIdx.x;
  __shared__ float w1s[C2 * HID];   // 32 KB
  __shared__ float w2s[HID * OUT_SZ];
  __shared__ float b1s[HID];
  __shared__ float b2s[OUT_SZ];

  for (int idx = b; idx < C2 * HID; idx += 256)
    w1s[idx] = fw1[(size_t)k * C2 * HID + idx];
  for (int idx = b; idx < HID * OUT_SZ; idx += 256)
    w2s[idx] = fw2[(size_t)k * HID * OUT_SZ + idx];
  if (b < HID) b1s[b] = fb1[k * HID + b];
  if (b < OUT_SZ) b2s[b] = fb2[k * OUT_SZ + b];
  __syncthreads();

  const unsigned short* xp =
      (const unsigned short*)h2 + (size_t)(b * K_NODES + k) * C2;

  float hid[HID];
#pragma unroll
  for (int j = 0; j < HID; ++j) hid[j] = b1s[j];
#pragma unroll
  for (int ch = 0; ch < C2 / 8; ++ch) {
    const us8 v = *(const us8*)(xp + ch * 8);
#pragma unroll
    for (int q = 0; q < 8; ++q) {
      const float xi = us2f(v[q]);
      const float* wr = &w1s[(ch * 8 + q) * HID];
#pragma unroll
      for (int j = 0; j < HID; ++j) hid[j] += xi * wr[j];
    }
  }
#pragma unroll
  for (int j = 0; j < HID; ++j) hid[j] = fmaxf(hid[j], 0.f);

  float o[OUT_SZ];
#pragma unroll
  for (int q = 0; q < OUT_SZ; ++q) o[q] = b2s[q];
  for (int j = 0; j < HID; ++j) {
    const float hj = hid[j];
    const float* wr = &w2s[j * OUT_SZ];
#pragma unroll
    for (int q = 0; q < OUT_SZ; ++q) o[q] += hj * wr[q];
  }

  float* dst = pred + ((size_t)k * B_GRAPHS + b) * OUT_SZ;
#pragma unroll
  for (int q = 0; q < OUT_SZ; ++q) dst[q] = o[q];
}

// ---------------------------------------------------------------------------
// yg = float(bf16(y)) in identical flat order (matches bf16-cast np reference).
// ---------------------------------------------------------------------------
__global__ __launch_bounds__(256)
void yg_kernel(const float* __restrict__ y, float* __restrict__ dst) {
  int i = (blockIdx.x * 256 + threadIdx.x) * 4;
  float4 v = *(const float4*)(y + i);
  v.x = __bfloat162float(__float2bfloat16(v.x));
  v.y = __bfloat162float(__float2bfloat16(v.y));
  v.z = __bfloat162float(__float2bfloat16(v.z));
  v.w = __bfloat162float(__float2bfloat16(v.w));
  *(float4*)(dst + i) = v;
}

// ---------------------------------------------------------------------------
extern "C" void kernel_launch(void* const* d_in, const int* in_sizes, int n_in,
                              void* d_out, int out_size, void* d_ws, size_t ws_size,
                              hipStream_t stream) {
  const float* x   = (const float*)d_in[0];
  const int*   ei  = (const int*)d_in[1];    // [2,E]: first E entries = src
  const float* y   = (const float*)d_in[3];
  const float* W1  = (const float*)d_in[4];
  const float* as1 = (const float*)d_in[5];
  const float* ad1 = (const float*)d_in[6];
  const float* b1  = (const float*)d_in[7];
  const float* W2  = (const float*)d_in[8];
  const float* as2 = (const float*)d_in[9];
  const float* ad2 = (const float*)d_in[10];
  const float* b2  = (const float*)d_in[11];
  const float* fw1 = (const float*)d_in[12];
  const float* fb1 = (const float*)d_in[13];
  const float* fw2 = (const float*)d_in[14];
  const float* fb2 = (const float*)d_in[15];

  // Workspace (~21 MB): [xl N*512 bf16][h N*128 bf16]
  bf16* xl   = (bf16*)d_ws;
  bf16* hbuf = xl + (size_t)N_NODES * 512;

  float* out = (float*)d_out;

  // ---- GAT layer 1: xl1 = x@W1 [N,400]; h1 = fused-att(xl1) [N,100] ----
  gemm_mfma<IN_F, IN_F, NHEADS * C1, float>
      <<<dim3((NHEADS * C1 + 63) / 64, N_NODES / 128), 256, 0, stream>>>(x, W1, xl);
  att_fused<C1, true><<<B_GRAPHS, 256, 0, stream>>>(xl, ei, as1, ad1, b1, hbuf);

  // ---- GAT layer 2: xl2 = h1@W2 [N,512]; h2 = fused-att(xl2) [N,128] ----
  gemm_mfma<C1, 128, NHEADS * C2, unsigned short>
      <<<dim3((NHEADS * C2 + 63) / 64, N_NODES / 128), 256, 0, stream>>>(
          (const unsigned short*)hbuf, W2, xl);
  att_fused<C2, false><<<B_GRAPHS, 256, 0, stream>>>(xl, ei, as2, ad2, b2, hbuf);

  // ---- per-node-index MLP head -> pred (chunk0, f32) ----
  mlp_kernel<<<K_NODES, 256, 0, stream>>>(hbuf, fw1, fb1, fw2, fb2, out);

  // ---- yg -> chunk1 ----
  yg_kernel<<<PRED_ELEMS / 4 / 256, 256, 0, stream>>>(y, out + PRED_ELEMS);
}

// Round 8
// 190.089 us; speedup vs baseline: 1.8765x; 1.8765x over previous
//
#include <hip/hip_runtime.h>
#include <hip/hip_bf16.h>
#include <math.h>

// Dtype model (pinned R0-R4): float inputs arrive f32; edge_index int32;
// d_out read as f32: chunk0 = pred f32[0:393216], chunk1 = yg f32[393216:786432];
// np reference computed from bf16-cast inputs -> bf16 intermediates are safe
// (R5-R7 passed at absmax 6.1e-5 vs threshold 9.25e-2).
//
// R7 lesson: full-unroll VALU MLP spilled (VGPR=256, 30MB scratch writes,
// 185us). This round: MFMA MLP, acc in 24 VGPRs.

#define N_NODES 16384
#define B_GRAPHS 256
#define K_NODES 64
#define DEG 8
#define NHEADS 4
#define C1 100
#define C2 128
#define IN_F 96
#define HID 64
#define OUT_SZ 24
#define PRED_ELEMS (K_NODES * B_GRAPHS * OUT_SZ)   // 393216

using bf16 = __hip_bfloat16;
typedef __attribute__((ext_vector_type(8))) short          frag_ab;  // 8 bf16
typedef __attribute__((ext_vector_type(4))) float          frag_cd;  // 4 f32
typedef unsigned short us8 __attribute__((ext_vector_type(8)));      // 16 B

__device__ __forceinline__ float ldf(const float* p) { return *p; }
__device__ __forceinline__ float ldf(const bf16* p) { return __bfloat162float(*p); }
__device__ __forceinline__ float us2f(unsigned short u) {
  return __bfloat162float(__ushort_as_bfloat16(u));
}
__device__ __forceinline__ short f2bf_s(float f) {
  return __builtin_bit_cast(short, __float2bfloat16(f));
}

// ---------------------------------------------------------------------------
// MFMA GEMM (verified R6): A [M,KDIM] (f32 or bf16-as-ushort) @ B [KDIM,NDIM]
// (f32) -> C bf16. BM=128 x BN=64, full K in LDS.
// ---------------------------------------------------------------------------
template<int KDIM, int KP, int NDIM, typename AT>
__global__ __launch_bounds__(256)
void gemm_mfma(const AT* __restrict__ A, const float* __restrict__ B,
               bf16* __restrict__ C) {
  constexpr int BM = 128, BN = 64;
  constexpr int LDA = KP + 8;
  constexpr int LDB = KP + 8;
  __shared__ __align__(16) short As[BM * LDA];
  __shared__ __align__(16) short Bs[BN * LDB];
  const int t  = threadIdx.x;
  const int m0 = blockIdx.y * BM;
  const int n0 = blockIdx.x * BN;

  if constexpr (sizeof(AT) == 4) {
    constexpr int QR = KDIM / 4;
    for (int idx = t; idx < BM * QR; idx += 256) {
      int m = idx / QR, q = idx - m * QR;
      const float4 v = *(const float4*)((const float*)A + (size_t)(m0 + m) * KDIM + q * 4);
      short* d = &As[m * LDA + q * 4];
      d[0] = f2bf_s(v.x); d[1] = f2bf_s(v.y); d[2] = f2bf_s(v.z); d[3] = f2bf_s(v.w);
    }
  } else {
    constexpr int PR = KDIM / 2;
    for (int idx = t; idx < BM * PR; idx += 256) {
      int m = idx / PR, p = idx - m * PR;
      const ushort2 v = *(const ushort2*)((const unsigned short*)A +
                                          (size_t)(m0 + m) * KDIM + p * 2);
      As[m * LDA + p * 2]     = (short)v.x;
      As[m * LDA + p * 2 + 1] = (short)v.y;
    }
    if constexpr (KP > KDIM) {
      constexpr int TR = KP - KDIM;
      for (int idx = t; idx < BM * TR; idx += 256) {
        int m = idx / TR, k = idx - m * TR;
        As[m * LDA + KDIM + k] = 0;
      }
    }
  }

  for (int idx = t; idx < KDIM * BN; idx += 256) {
    int k = idx >> 6, n = idx & 63;
    int gn = n0 + n;
    float v = (gn < NDIM) ? B[(size_t)k * NDIM + gn] : 0.f;
    Bs[n * LDB + k] = f2bf_s(v);
  }
  if constexpr (KP > KDIM) {
    constexpr int TR = KP - KDIM;
    for (int idx = t; idx < BN * TR; idx += 256) {
      int n = idx / TR, k = KDIM + (idx - n * TR);
      Bs[n * LDB + k] = 0;
    }
  }
  __syncthreads();

  const int wv = t >> 6;
  const int l  = t & 63;
  const int lm = l & 15;
  const int lk = (l >> 4) * 8;
  const int mw = wv * 32;

  frag_cd acc[2][4] = {};
#pragma unroll
  for (int ks = 0; ks < KP; ks += 32) {
    frag_ab a[2], b[4];
#pragma unroll
    for (int mt = 0; mt < 2; ++mt)
      a[mt] = *(const frag_ab*)&As[(mw + mt * 16 + lm) * LDA + ks + lk];
#pragma unroll
    for (int nt = 0; nt < 4; ++nt)
      b[nt] = *(const frag_ab*)&Bs[(nt * 16 + lm) * LDB + ks + lk];
#pragma unroll
    for (int mt = 0; mt < 2; ++mt)
#pragma unroll
      for (int nt = 0; nt < 4; ++nt)
        acc[mt][nt] = __builtin_amdgcn_mfma_f32_16x16x32_bf16(
            a[mt], b[nt], acc[mt][nt], 0, 0, 0);
  }

  const int rq = (l >> 4) * 4;
#pragma unroll
  for (int mt = 0; mt < 2; ++mt) {
#pragma unroll
    for (int nt = 0; nt < 4; ++nt) {
      int gn = n0 + nt * 16 + lm;
      if (gn < NDIM) {
#pragma unroll
        for (int r = 0; r < 4; ++r) {
          int gm = m0 + mw + mt * 16 + rq + r;
          C[(size_t)gm * NDIM + gn] = __float2bfloat16(acc[mt][nt][r]);
        }
      }
    }
  }
}

// ---------------------------------------------------------------------------
// Fused per-graph attention (R7, passed): one block per graph. Slab in LDS,
// logits + 9-edge softmax + aggregation + head-mean + bias (+ELU) from LDS.
// ---------------------------------------------------------------------------
template<int C, bool ELU>
__global__ __launch_bounds__(256)
void att_fused(const bf16* __restrict__ xl, const int* __restrict__ esrc,
               const float* __restrict__ a_src, const float* __restrict__ a_dst,
               const float* __restrict__ bias, bf16* __restrict__ out) {
  constexpr int C4  = NHEADS * C;
  constexpr int LDX = C4 + 8;
  __shared__ __align__(16) unsigned short xs[K_NODES * LDX];
  __shared__ float avs[C4], avd[C4];
  __shared__ float bia[C];
  __shared__ int   edg[K_NODES * DEG];
  __shared__ float als[K_NODES][NHEADS], ald[K_NODES][NHEADS];
  __shared__ float w[K_NODES][NHEADS * 9];

  const int g = blockIdx.x;
  const int t = threadIdx.x;

  const unsigned short* slab = (const unsigned short*)xl + (size_t)g * K_NODES * C4;
  constexpr int CPR = C4 / 8;
  for (int cidx = t; cidx < K_NODES * CPR; cidx += 256) {
    int r = cidx / CPR, o = cidx - r * CPR;
    *(us8*)&xs[r * LDX + o * 8] = *(const us8*)(slab + (size_t)cidx * 8);
  }
  for (int idx = t; idx < C4; idx += 256) {
    avs[idx] = a_src[idx];
    avd[idx] = a_dst[idx];
  }
  if (t < C) bia[t] = bias[t];
  for (int idx = t; idx < K_NODES * DEG; idx += 256)
    edg[idx] = esrc[g * K_NODES * DEG + idx] & (K_NODES - 1);
  __syncthreads();

  {
    const int n = t >> 2, h = t & 3;
    const unsigned short* row = &xs[n * LDX + h * C];
    const float* pas = &avs[h * C];
    const float* pad = &avd[h * C];
    float ss = 0.f, sd = 0.f;
    for (int c = 0; c < C; ++c) {
      float v = us2f(row[c]);
      ss += v * pas[c];
      sd += v * pad[c];
    }
    als[n][h] = ss;
    ald[n][h] = sd;
  }
  __syncthreads();

  {
    const int n = t >> 2, h = t & 3;
    float a[9];
    const float ad = ald[n][h];
#pragma unroll
    for (int j = 0; j < 8; ++j) {
      float v = als[edg[n * DEG + j]][h] + ad;
      a[j] = (v >= 0.f) ? v : 0.2f * v;
    }
    {
      float v = als[n][h] + ad;
      a[8] = (v >= 0.f) ? v : 0.2f * v;
    }
    float m = -1e30f;
#pragma unroll
    for (int j = 0; j < 9; ++j) m = fmaxf(m, a[j]);
    float s = 0.f;
#pragma unroll
    for (int j = 0; j < 9; ++j) { a[j] = __expf(a[j] - m); s += a[j]; }
    float inv = 1.f / (s + 1e-16f);
#pragma unroll
    for (int j = 0; j < 9; ++j) w[n][h * 9 + j] = a[j] * inv;
  }
  __syncthreads();

  for (int idx = t; idx < K_NODES * C; idx += 256) {
    const int n = idx / C, c = idx - n * C;
    int s[9];
#pragma unroll
    for (int j = 0; j < 8; ++j) s[j] = edg[n * DEG + j];
    s[8] = n;
    float acc = 0.f;
#pragma unroll
    for (int h = 0; h < NHEADS; ++h) {
      const float* wn = &w[n][h * 9];
      float hacc = 0.f;
#pragma unroll
      for (int j = 0; j < 9; ++j)
        hacc += wn[j] * us2f(xs[s[j] * LDX + h * C + c]);
      acc += hacc;
    }
    acc = acc * 0.25f + bia[c];
    if (ELU) acc = (acc > 0.f) ? acc : (__expf(acc) - 1.f);
    out[((size_t)g * K_NODES + n) * C + c] = __float2bfloat16(acc);
  }
}

// ---------------------------------------------------------------------------
// MFMA MLP head. Grid 256 = (k in [0,64)) x (ms in [0,4)): block handles
// rows b in [ms*64, ms*64+64) of xg[k] = h2[b*64+k, :].
//   hid = relu(xg[k] @ fw1[k] + fb1[k])   [64 x 64]   (K=128, 4 ksteps)
//   pred[k,b,:] = hid @ fw2[k] + fb2[k]   [64 x 24]   (K=64, N padded to 32)
// Wave wv owns 16 rows; acc frags: 4 + 2 = 24 VGPRs. No spill (R7 lesson).
// ---------------------------------------------------------------------------
__global__ __launch_bounds__(256)
void mlp_mfma(const bf16* __restrict__ h2,
              const float* __restrict__ fw1, const float* __restrict__ fb1,
              const float* __restrict__ fw2, const float* __restrict__ fb2,
              float* __restrict__ pred) {
  constexpr int LDA = C2 + 8;      // 136 shorts, rows 16B-aligned
  constexpr int LDH = HID + 8;     // 72
  __shared__ __align__(16) short As[64 * LDA];     // 17 KB
  __shared__ __align__(16) short B1[HID * LDA];    // fw1^T [n=64][k=128], 17 KB
  __shared__ __align__(16) short Hs[64 * LDH];     // hid [m][k2], 9 KB
  __shared__ __align__(16) short B2[32 * LDH];     // fw2^T [n=32][k2=64], 4.5 KB
  __shared__ float b1s[HID];
  __shared__ float b2s[32];

  const int k  = blockIdx.x & 63;
  const int ms = blockIdx.x >> 6;
  const int t  = threadIdx.x;

  // stage A: row r -> h2[((ms*64+r)*64 + k) * 128 ...], 16 chunks of 16B
  for (int idx = t; idx < 64 * 16; idx += 256) {
    int r = idx >> 4, o = idx & 15;
    const us8 v = *(const us8*)((const unsigned short*)h2 +
        ((size_t)((ms * 64 + r) * K_NODES + k) * C2) + o * 8);
    *(us8*)&As[r * LDA + o * 8] = __builtin_bit_cast(us8, v);
  }
  // stage B1 transposed (coalesced reads over n)
  for (int idx = t; idx < C2 * HID; idx += 256) {
    int kk = idx >> 6, n = idx & 63;
    B1[n * LDA + kk] = f2bf_s(fw1[(size_t)k * C2 * HID + kk * HID + n]);
  }
  // stage B2 transposed, n padded 24 -> 32
  for (int idx = t; idx < HID * 32; idx += 256) {
    int kk = idx >> 5, n = idx & 31;
    float v = (n < OUT_SZ) ? fw2[(size_t)k * HID * OUT_SZ + kk * OUT_SZ + n] : 0.f;
    B2[n * LDH + kk] = f2bf_s(v);
  }
  if (t < HID) b1s[t] = fb1[k * HID + t];
  if (t < 32)  b2s[t] = (t < OUT_SZ) ? fb2[k * OUT_SZ + t] : 0.f;
  __syncthreads();

  const int wv = t >> 6;
  const int l  = t & 63;
  const int lm = l & 15;
  const int lk = (l >> 4) * 8;
  const int rq = (l >> 4) * 4;

  // ---- GEMM1: [16 rows x 64 cols], K=128 ----
  frag_cd acc[4] = {};
#pragma unroll
  for (int ks = 0; ks < C2; ks += 32) {
    frag_ab a = *(const frag_ab*)&As[(wv * 16 + lm) * LDA + ks + lk];
#pragma unroll
    for (int nt = 0; nt < 4; ++nt) {
      frag_ab b = *(const frag_ab*)&B1[(nt * 16 + lm) * LDA + ks + lk];
      acc[nt] = __builtin_amdgcn_mfma_f32_16x16x32_bf16(a, b, acc[nt], 0, 0, 0);
    }
  }
  // bias + relu -> Hs (A-layout for GEMM2); C-frag: col=lane&15, row=quad*4+r
#pragma unroll
  for (int nt = 0; nt < 4; ++nt) {
    const int j  = nt * 16 + lm;
    const float bj = b1s[j];
#pragma unroll
    for (int r = 0; r < 4; ++r) {
      const int m = wv * 16 + rq + r;
      Hs[m * LDH + j] = f2bf_s(fmaxf(acc[nt][r] + bj, 0.f));
    }
  }
  __syncthreads();

  // ---- GEMM2: [16 rows x 32 cols], K=64 ----
  frag_cd acc2[2] = {};
#pragma unroll
  for (int ks = 0; ks < HID; ks += 32) {
    frag_ab a = *(const frag_ab*)&Hs[(wv * 16 + lm) * LDH + ks + lk];
#pragma unroll
    for (int nt = 0; nt < 2; ++nt) {
      frag_ab b = *(const frag_ab*)&B2[(nt * 16 + lm) * LDH + ks + lk];
      acc2[nt] = __builtin_amdgcn_mfma_f32_16x16x32_bf16(a, b, acc2[nt], 0, 0, 0);
    }
  }
  // store pred[(k*256 + ms*64 + m) * 24 + q]
#pragma unroll
  for (int nt = 0; nt < 2; ++nt) {
    const int q = nt * 16 + lm;
    if (q < OUT_SZ) {
      const float bq = b2s[q];
#pragma unroll
      for (int r = 0; r < 4; ++r) {
        const int m = wv * 16 + rq + r;
        pred[((size_t)k * B_GRAPHS + ms * 64 + m) * OUT_SZ + q] = acc2[nt][r] + bq;
      }
    }
  }
}

// ---------------------------------------------------------------------------
// yg = float(bf16(y)) in identical flat order (matches bf16-cast np reference).
// ---------------------------------------------------------------------------
__global__ __launch_bounds__(256)
void yg_kernel(const float* __restrict__ y, float* __restrict__ dst) {
  int i = (blockIdx.x * 256 + threadIdx.x) * 4;
  float4 v = *(const float4*)(y + i);
  v.x = __bfloat162float(__float2bfloat16(v.x));
  v.y = __bfloat162float(__float2bfloat16(v.y));
  v.z = __bfloat162float(__float2bfloat16(v.z));
  v.w = __bfloat162float(__float2bfloat16(v.w));
  *(float4*)(dst + i) = v;
}

// ---------------------------------------------------------------------------
extern "C" void kernel_launch(void* const* d_in, const int* in_sizes, int n_in,
                              void* d_out, int out_size, void* d_ws, size_t ws_size,
                              hipStream_t stream) {
  const float* x   = (const float*)d_in[0];
  const int*   ei  = (const int*)d_in[1];
  const float* y   = (const float*)d_in[3];
  const float* W1  = (const float*)d_in[4];
  const float* as1 = (const float*)d_in[5];
  const float* ad1 = (const float*)d_in[6];
  const float* b1  = (const float*)d_in[7];
  const float* W2  = (const float*)d_in[8];
  const float* as2 = (const float*)d_in[9];
  const float* ad2 = (const float*)d_in[10];
  const float* b2  = (const float*)d_in[11];
  const float* fw1 = (const float*)d_in[12];
  const float* fb1 = (const float*)d_in[13];
  const float* fw2 = (const float*)d_in[14];
  const float* fb2 = (const float*)d_in[15];

  // Workspace (~21 MB): [xl N*512 bf16][h N*128 bf16]
  bf16* xl   = (bf16*)d_ws;
  bf16* hbuf = xl + (size_t)N_NODES * 512;

  float* out = (float*)d_out;

  // ---- GAT layer 1 ----
  gemm_mfma<IN_F, IN_F, NHEADS * C1, float>
      <<<dim3((NHEADS * C1 + 63) / 64, N_NODES / 128), 256, 0, stream>>>(x, W1, xl);
  att_fused<C1, true><<<B_GRAPHS, 256, 0, stream>>>(xl, ei, as1, ad1, b1, hbuf);

  // ---- GAT layer 2 ----
  gemm_mfma<C1, 128, NHEADS * C2, unsigned short>
      <<<dim3((NHEADS * C2 + 63) / 64, N_NODES / 128), 256, 0, stream>>>(
          (const unsigned short*)hbuf, W2, xl);
  att_fused<C2, false><<<B_GRAPHS, 256, 0, stream>>>(xl, ei, as2, ad2, b2, hbuf);

  // ---- MFMA MLP head -> pred (chunk0, f32) ----
  mlp_mfma<<<K_NODES * 4, 256, 0, stream>>>(hbuf, fw1, fb1, fw2, fb2, out);

  // ---- yg -> chunk1 ----
  yg_kernel<<<PRED_ELEMS / 4 / 256, 256, 0, stream>>>(y, out + PRED_ELEMS);
}

// Round 9
// 156.897 us; speedup vs baseline: 2.2735x; 1.2116x over previous
//
#include <hip/hip_runtime.h>
#include <hip/hip_bf16.h>
#include <math.h>

// Dtype model (pinned R0-R4): float inputs arrive f32; edge_index int32;
// d_out read as f32: chunk0 = pred f32[0:393216], chunk1 = yg f32[393216:786432];
// np reference computed from bf16-cast inputs -> bf16 intermediates are safe
// (R5-R8 passed at absmax 6.1e-5 vs threshold 9.25e-2).
//
// R7 lesson: register spills kill (VGPR=256 -> 30MB scratch, 185us).
// R8: 190us across 6 kernels. This round: GAT layer is graph-local ->
// fuse gemm+attention per graph (1 block/graph, grid=256=CU count), xl slab
// lives in LDS only. 6 kernels -> 4; xl HBM round-trip (~60MB) eliminated;
// attention loops vectorized (ds_read_b64/b128 instead of scalar b16).

#define N_NODES 16384
#define B_GRAPHS 256
#define K_NODES 64
#define DEG 8
#define NHEADS 4
#define C1 100
#define C2 128
#define IN_F 96
#define HID 64
#define OUT_SZ 24
#define PRED_ELEMS (K_NODES * B_GRAPHS * OUT_SZ)   // 393216

using bf16 = __hip_bfloat16;
typedef __attribute__((ext_vector_type(8))) short          frag_ab;  // 8 bf16
typedef __attribute__((ext_vector_type(4))) float          frag_cd;  // 4 f32
typedef unsigned short us8 __attribute__((ext_vector_type(8)));      // 16 B
typedef unsigned short us4 __attribute__((ext_vector_type(4)));      // 8 B

__device__ __forceinline__ float us2f(unsigned short u) {
  return __bfloat162float(__ushort_as_bfloat16(u));
}
__device__ __forceinline__ short f2bf_s(float f) {
  return __builtin_bit_cast(short, __float2bfloat16(f));
}

// ---------------------------------------------------------------------------
// Fused GAT layer, one block per graph. A [N,KDIM] node feats (f32 or
// bf16-as-ushort), W [KDIM, 4C] f32. Computes xl = A_g @ W into LDS via MFMA
// (64-col chunks), then attention logits + 9-edge softmax + aggregation +
// head-mean + bias (+ELU), writing h [64,C] bf16 to global.
// ---------------------------------------------------------------------------
template<int KDIM, int KP, int C, bool ELU, typename AT>
__global__ __launch_bounds__(256)
void gat_layer(const AT* __restrict__ A, const float* __restrict__ W,
               const int* __restrict__ esrc,
               const float* __restrict__ a_src, const float* __restrict__ a_dst,
               const float* __restrict__ bias, bf16* __restrict__ out) {
  constexpr int C4  = NHEADS * C;          // 400 / 512
  constexpr int LDA = KP + 8;              // 104 / 136 (shorts, rows 16B-aligned)
  constexpr int LDX = C4 + 8;              // 408 / 520
  constexpr int NCH = (C4 + 63) / 64;      // 7 / 8 column chunks
  constexpr int GR  = (C % 8 == 0) ? 8 : 4;
  constexpr int NG  = C / GR;              // 25 / 16

  __shared__ __align__(16) short          As[64 * LDA];   // input slab (bf16)
  __shared__ __align__(16) short          Bs[64 * LDA];   // W chunk, n-major k-contig
  __shared__ __align__(16) unsigned short xs[64 * LDX];   // xl slab (bf16 bits)
  __shared__ float avs[C4], avd[C4], bia[C];
  __shared__ int   edg[K_NODES * DEG];
  __shared__ float als[64][4], ald[64][4];
  __shared__ float w[64][36];

  const int g = blockIdx.x;
  const int t = threadIdx.x;

  // ---- phase 0: stage input slab + params ----
  if constexpr (sizeof(AT) == 4) {
    constexpr int QR = KDIM / 4;           // 24 (layer 1, K=96, f32)
    for (int idx = t; idx < 64 * QR; idx += 256) {
      int m = idx / QR, q = idx - m * QR;
      const float4 v = *(const float4*)((const float*)A +
                                        ((size_t)(g * 64 + m) * KDIM + q * 4));
      short* d = &As[m * LDA + q * 4];
      d[0] = f2bf_s(v.x); d[1] = f2bf_s(v.y); d[2] = f2bf_s(v.z); d[3] = f2bf_s(v.w);
    }
  } else {
    constexpr int PR = KDIM / 2;           // 50 (layer 2, K=100, bf16)
    for (int idx = t; idx < 64 * PR; idx += 256) {
      int m = idx / PR, p = idx - m * PR;
      const ushort2 v = *(const ushort2*)((const unsigned short*)A +
                                          ((size_t)(g * 64 + m) * KDIM + p * 2));
      As[m * LDA + p * 2]     = (short)v.x;
      As[m * LDA + p * 2 + 1] = (short)v.y;
    }
  }
  if constexpr (KP > KDIM) {
    constexpr int TR = KP - KDIM;
    for (int idx = t; idx < 64 * TR; idx += 256) {
      int m = idx / TR, kk = idx - m * TR;
      As[m * LDA + KDIM + kk] = 0;
    }
  }
  for (int idx = t; idx < C4; idx += 256) { avs[idx] = a_src[idx]; avd[idx] = a_dst[idx]; }
  for (int idx = t; idx < C;  idx += 256) bia[idx] = bias[idx];
  for (int idx = t; idx < K_NODES * DEG; idx += 256)
    edg[idx] = esrc[g * K_NODES * DEG + idx] & (K_NODES - 1);
  __syncthreads();

  const int wv = t >> 6;
  const int l  = t & 63;
  const int lm = l & 15;
  const int lk = (l >> 4) * 8;
  const int rq = (l >> 4) * 4;
  const int mw = wv * 16;                  // wave's 16 rows

  // ---- phase 1: xl = As @ W -> xs (LDS), 64-col chunks ----
  for (int ch = 0; ch < NCH; ++ch) {
    const int n0 = ch * 64;
    for (int idx = t; idx < KDIM * 64; idx += 256) {
      int k = idx >> 6, n = idx & 63, gn = n0 + n;
      Bs[n * LDA + k] = (gn < C4) ? f2bf_s(W[(size_t)k * C4 + gn]) : (short)0;
    }
    if constexpr (KP > KDIM) {
      constexpr int TR = KP - KDIM;
      for (int idx = t; idx < 64 * TR; idx += 256) {
        int n = idx / TR, kk = idx - n * TR;
        Bs[n * LDA + KDIM + kk] = 0;
      }
    }
    __syncthreads();

    frag_cd acc[4] = {};
#pragma unroll
    for (int ks = 0; ks < KP; ks += 32) {
      frag_ab a = *(const frag_ab*)&As[(mw + lm) * LDA + ks + lk];
#pragma unroll
      for (int nt = 0; nt < 4; ++nt) {
        frag_ab b = *(const frag_ab*)&Bs[(nt * 16 + lm) * LDA + ks + lk];
        acc[nt] = __builtin_amdgcn_mfma_f32_16x16x32_bf16(a, b, acc[nt], 0, 0, 0);
      }
    }
    // C-frag: col = lane&15, row = quad*4 + r (verified layout)
#pragma unroll
    for (int nt = 0; nt < 4; ++nt) {
      const int c = n0 + nt * 16 + lm;
      if (c < C4) {
#pragma unroll
        for (int r = 0; r < 4; ++r)
          xs[(mw + rq + r) * LDX + c] = (unsigned short)f2bf_s(acc[nt][r]);
      }
    }
    __syncthreads();   // xs written; Bs safe to overwrite next chunk
  }

  // ---- phase 2: attention logits, thread = (node, head), vector LDS reads ----
  {
    const int n = t >> 2, h = t & 3;
    float ss = 0.f, sd = 0.f;
    for (int c0 = 0; c0 < C; c0 += GR) {
      if constexpr (GR == 8) {
        const us8 v = *(const us8*)&xs[n * LDX + h * C + c0];
        const float4 p0 = *(const float4*)&avs[h * C + c0];
        const float4 p1 = *(const float4*)&avs[h * C + c0 + 4];
        const float4 q0 = *(const float4*)&avd[h * C + c0];
        const float4 q1 = *(const float4*)&avd[h * C + c0 + 4];
        ss += us2f(v[0]) * p0.x + us2f(v[1]) * p0.y + us2f(v[2]) * p0.z + us2f(v[3]) * p0.w
            + us2f(v[4]) * p1.x + us2f(v[5]) * p1.y + us2f(v[6]) * p1.z + us2f(v[7]) * p1.w;
        sd += us2f(v[0]) * q0.x + us2f(v[1]) * q0.y + us2f(v[2]) * q0.z + us2f(v[3]) * q0.w
            + us2f(v[4]) * q1.x + us2f(v[5]) * q1.y + us2f(v[6]) * q1.z + us2f(v[7]) * q1.w;
      } else {
        const us4 v = *(const us4*)&xs[n * LDX + h * C + c0];
        const float4 p = *(const float4*)&avs[h * C + c0];
        const float4 q = *(const float4*)&avd[h * C + c0];
        ss += us2f(v[0]) * p.x + us2f(v[1]) * p.y + us2f(v[2]) * p.z + us2f(v[3]) * p.w;
        sd += us2f(v[0]) * q.x + us2f(v[1]) * q.y + us2f(v[2]) * q.z + us2f(v[3]) * q.w;
      }
    }
    als[n][h] = ss;
    ald[n][h] = sd;
  }
  __syncthreads();

  // ---- phase 3: 9-edge softmax (8 edges + self-loop), thread = (node, head) ----
  {
    const int n = t >> 2, h = t & 3;
    float a[9];
    const float ad = ald[n][h];
#pragma unroll
    for (int j = 0; j < 8; ++j) {
      float v = als[edg[n * DEG + j]][h] + ad;
      a[j] = (v >= 0.f) ? v : 0.2f * v;    // leaky_relu 0.2
    }
    {
      float v = als[n][h] + ad;
      a[8] = (v >= 0.f) ? v : 0.2f * v;
    }
    float m = -1e30f;
#pragma unroll
    for (int j = 0; j < 9; ++j) m = fmaxf(m, a[j]);
    float s = 0.f;
#pragma unroll
    for (int j = 0; j < 9; ++j) { a[j] = __expf(a[j] - m); s += a[j]; }
    float inv = 1.f / (s + 1e-16f);
#pragma unroll
    for (int j = 0; j < 9; ++j) w[n][h * 9 + j] = a[j] * inv;
  }
  __syncthreads();

  // ---- phase 4: aggregation + head-mean + bias (+ELU), vector LDS reads ----
  for (int idx = t; idx < 64 * NG; idx += 256) {
    const int n = idx / NG, c0 = (idx - n * NG) * GR;
    int s[9];
#pragma unroll
    for (int j = 0; j < 8; ++j) s[j] = edg[n * DEG + j];
    s[8] = n;
    float acc[GR] = {};
#pragma unroll
    for (int h = 0; h < NHEADS; ++h) {
#pragma unroll
      for (int j = 0; j < 9; ++j) {
        const float wj = w[n][h * 9 + j];
        if constexpr (GR == 8) {
          const us8 v = *(const us8*)&xs[s[j] * LDX + h * C + c0];
#pragma unroll
          for (int i = 0; i < 8; ++i) acc[i] += wj * us2f(v[i]);
        } else {
          const us4 v = *(const us4*)&xs[s[j] * LDX + h * C + c0];
#pragma unroll
          for (int i = 0; i < 4; ++i) acc[i] += wj * us2f(v[i]);
        }
      }
    }
    unsigned short* dst = (unsigned short*)out + ((size_t)g * 64 + n) * C + c0;
    if constexpr (GR == 8) {
      us8 o;
#pragma unroll
      for (int i = 0; i < 8; ++i) {
        float vv = acc[i] * 0.25f + bia[c0 + i];
        if (ELU) vv = (vv > 0.f) ? vv : (__expf(vv) - 1.f);
        o[i] = (unsigned short)f2bf_s(vv);
      }
      *(us8*)dst = o;
    } else {
      us4 o;
#pragma unroll
      for (int i = 0; i < 4; ++i) {
        float vv = acc[i] * 0.25f + bia[c0 + i];
        if (ELU) vv = (vv > 0.f) ? vv : (__expf(vv) - 1.f);
        o[i] = (unsigned short)f2bf_s(vv);
      }
      *(us4*)dst = o;
    }
  }
}

// ---------------------------------------------------------------------------
// MFMA MLP head (verified R8). Grid 256 = (k) x (ms): block handles rows
// b in [ms*64, ms*64+64) of xg[k] = h2[b*64+k, :].
// ---------------------------------------------------------------------------
__global__ __launch_bounds__(256)
void mlp_mfma(const bf16* __restrict__ h2,
              const float* __restrict__ fw1, const float* __restrict__ fb1,
              const float* __restrict__ fw2, const float* __restrict__ fb2,
              float* __restrict__ pred) {
  constexpr int LDA = C2 + 8;
  constexpr int LDH = HID + 8;
  __shared__ __align__(16) short As[64 * LDA];
  __shared__ __align__(16) short B1[HID * LDA];
  __shared__ __align__(16) short Hs[64 * LDH];
  __shared__ __align__(16) short B2[32 * LDH];
  __shared__ float b1s[HID];
  __shared__ float b2s[32];

  const int k  = blockIdx.x & 63;
  const int ms = blockIdx.x >> 6;
  const int t  = threadIdx.x;

  for (int idx = t; idx < 64 * 16; idx += 256) {
    int r = idx >> 4, o = idx & 15;
    const us8 v = *(const us8*)((const unsigned short*)h2 +
        ((size_t)((ms * 64 + r) * K_NODES + k) * C2) + o * 8);
    *(us8*)&As[r * LDA + o * 8] = v;
  }
  for (int idx = t; idx < C2 * HID; idx += 256) {
    int kk = idx >> 6, n = idx & 63;
    B1[n * LDA + kk] = f2bf_s(fw1[(size_t)k * C2 * HID + kk * HID + n]);
  }
  for (int idx = t; idx < HID * 32; idx += 256) {
    int kk = idx >> 5, n = idx & 31;
    float v = (n < OUT_SZ) ? fw2[(size_t)k * HID * OUT_SZ + kk * OUT_SZ + n] : 0.f;
    B2[n * LDH + kk] = f2bf_s(v);
  }
  if (t < HID) b1s[t] = fb1[k * HID + t];
  if (t < 32)  b2s[t] = (t < OUT_SZ) ? fb2[k * OUT_SZ + t] : 0.f;
  __syncthreads();

  const int wv = t >> 6;
  const int l  = t & 63;
  const int lm = l & 15;
  const int lk = (l >> 4) * 8;
  const int rq = (l >> 4) * 4;

  frag_cd acc[4] = {};
#pragma unroll
  for (int ks = 0; ks < C2; ks += 32) {
    frag_ab a = *(const frag_ab*)&As[(wv * 16 + lm) * LDA + ks + lk];
#pragma unroll
    for (int nt = 0; nt < 4; ++nt) {
      frag_ab b = *(const frag_ab*)&B1[(nt * 16 + lm) * LDA + ks + lk];
      acc[nt] = __builtin_amdgcn_mfma_f32_16x16x32_bf16(a, b, acc[nt], 0, 0, 0);
    }
  }
#pragma unroll
  for (int nt = 0; nt < 4; ++nt) {
    const int j  = nt * 16 + lm;
    const float bj = b1s[j];
#pragma unroll
    for (int r = 0; r < 4; ++r) {
      const int m = wv * 16 + rq + r;
      Hs[m * LDH + j] = f2bf_s(fmaxf(acc[nt][r] + bj, 0.f));
    }
  }
  __syncthreads();

  frag_cd acc2[2] = {};
#pragma unroll
  for (int ks = 0; ks < HID; ks += 32) {
    frag_ab a = *(const frag_ab*)&Hs[(wv * 16 + lm) * LDH + ks + lk];
#pragma unroll
    for (int nt = 0; nt < 2; ++nt) {
      frag_ab b = *(const frag_ab*)&B2[(nt * 16 + lm) * LDH + ks + lk];
      acc2[nt] = __builtin_amdgcn_mfma_f32_16x16x32_bf16(a, b, acc2[nt], 0, 0, 0);
    }
  }
#pragma unroll
  for (int nt = 0; nt < 2; ++nt) {
    const int q = nt * 16 + lm;
    if (q < OUT_SZ) {
      const float bq = b2s[q];
#pragma unroll
      for (int r = 0; r < 4; ++r) {
        const int m = wv * 16 + rq + r;
        pred[((size_t)k * B_GRAPHS + ms * 64 + m) * OUT_SZ + q] = acc2[nt][r] + bq;
      }
    }
  }
}

// ---------------------------------------------------------------------------
// yg = float(bf16(y)) in identical flat order (matches bf16-cast np reference).
// ---------------------------------------------------------------------------
__global__ __launch_bounds__(256)
void yg_kernel(const float* __restrict__ y, float* __restrict__ dst) {
  int i = (blockIdx.x * 256 + threadIdx.x) * 4;
  float4 v = *(const float4*)(y + i);
  v.x = __bfloat162float(__float2bfloat16(v.x));
  v.y = __bfloat162float(__float2bfloat16(v.y));
  v.z = __bfloat162float(__float2bfloat16(v.z));
  v.w = __bfloat162float(__float2bfloat16(v.w));
  *(float4*)(dst + i) = v;
}

// ---------------------------------------------------------------------------
extern "C" void kernel_launch(void* const* d_in, const int* in_sizes, int n_in,
                              void* d_out, int out_size, void* d_ws, size_t ws_size,
                              hipStream_t stream) {
  const float* x   = (const float*)d_in[0];
  const int*   ei  = (const int*)d_in[1];    // [2,E]: first E entries = src
  const float* y   = (const float*)d_in[3];
  const float* W1  = (const float*)d_in[4];
  const float* as1 = (const float*)d_in[5];
  const float* ad1 = (const float*)d_in[6];
  const float* b1  = (const float*)d_in[7];
  const float* W2  = (const float*)d_in[8];
  const float* as2 = (const float*)d_in[9];
  const float* ad2 = (const float*)d_in[10];
  const float* b2  = (const float*)d_in[11];
  const float* fw1 = (const float*)d_in[12];
  const float* fb1 = (const float*)d_in[13];
  const float* fw2 = (const float*)d_in[14];
  const float* fb2 = (const float*)d_in[15];

  // Workspace: h1 [N,100] bf16, h2 [N,128] bf16 (separate: no cross-block hazard)
  bf16* h1 = (bf16*)d_ws;
  bf16* h2 = h1 + (size_t)N_NODES * C1;

  float* out = (float*)d_out;

  // ---- fused GAT layer 1: h1 = att(x @ W1), per-graph blocks ----
  gat_layer<IN_F, IN_F, C1, true, float>
      <<<B_GRAPHS, 256, 0, stream>>>(x, W1, ei, as1, ad1, b1, h1);

  // ---- fused GAT layer 2: h2 = att(h1 @ W2) ----
  gat_layer<C1, 128, C2, false, unsigned short>
      <<<B_GRAPHS, 256, 0, stream>>>((const unsigned short*)h1, W2, ei,
                                     as2, ad2, b2, h2);

  // ---- MFMA MLP head -> pred (chunk0, f32) ----
  mlp_mfma<<<K_NODES * 4, 256, 0, stream>>>(h2, fw1, fb1, fw2, fb2, out);

  // ---- yg -> chunk1 ----
  yg_kernel<<<PRED_ELEMS / 4 / 256, 256, 0, stream>>>(y, out + PRED_ELEMS);
}

// Round 10
// 127.427 us; speedup vs baseline: 2.7993x; 1.2313x over previous
//
#include <hip/hip_runtime.h>
#include <hip/hip_bf16.h>
#include <math.h>

// Dtype model (pinned R0-R4): float inputs f32; edge_index int32; d_out read
// as f32: chunk0 = pred f32[0:393216], chunk1 = yg f32[393216:786432]; np
// reference is computed from bf16-cast inputs -> bf16 intermediates safe.
//
// R7 lesson: dynamic-indexed local arrays / big unrolls spill -> scratch storm.
// R9 lesson: strided us8 LDS reads in attention = 3.6M bank conflicts, 42us.
// This round: xs transposed (lane-per-node reads free), aggregation via dense
// per-head P[64x64] @ X MFMA, W^T prepacked bf16 so GEMM B-frags come straight
// from L2.

#define N_NODES 16384
#define B_GRAPHS 256
#define K_NODES 64
#define DEG 8
#define NHEADS 4
#define C1 100
#define C2 128
#define IN_F 96
#define HID 64
#define OUT_SZ 24
#define PRED_ELEMS (K_NODES * B_GRAPHS * OUT_SZ)   // 393216

#define W1T_ROWS 448   // 400 cols padded to 7*64
#define W1T_K    96
#define W2T_ROWS 512
#define W2T_K    128   // 100 padded

using bf16 = __hip_bfloat16;
typedef __attribute__((ext_vector_type(8))) short          frag_ab;  // 8 bf16
typedef __attribute__((ext_vector_type(4))) float          frag_cd;  // 4 f32
typedef unsigned short us8 __attribute__((ext_vector_type(8)));      // 16 B
typedef unsigned short us4 __attribute__((ext_vector_type(4)));      // 8 B

__device__ __forceinline__ float us2f(unsigned short u) {
  return __bfloat162float(__ushort_as_bfloat16(u));
}
__device__ __forceinline__ short f2bf_s(float f) {
  return __builtin_bit_cast(short, __float2bfloat16(f));
}

// ---------------------------------------------------------------------------
// Prepack W1, W2 as W^T bf16: [C4P rows][KP] k-contiguous, zero-padded.
// ---------------------------------------------------------------------------
__global__ __launch_bounds__(256)
void pack_w(const float* __restrict__ W1, const float* __restrict__ W2,
            bf16* __restrict__ W1t, bf16* __restrict__ W2t) {
  int idx = blockIdx.x * 256 + threadIdx.x;
  if (idx < W1T_ROWS * W1T_K) {
    int c = idx / W1T_K, k = idx - c * W1T_K;
    W1t[idx] = __float2bfloat16((c < 400) ? W1[(size_t)k * 400 + c] : 0.f);
  } else {
    int i2 = idx - W1T_ROWS * W1T_K;
    if (i2 < W2T_ROWS * W2T_K) {
      int c = i2 >> 7, k = i2 & 127;
      W2t[i2] = __float2bfloat16((k < 100) ? W2[(size_t)k * 512 + c] : 0.f);
    }
  }
}

// ---------------------------------------------------------------------------
// Fused GAT layer, one block per graph (grid=256). Phases:
//  0: stage input slab As (bf16, k-padded), params, edges; zero P.
//  1: xl = As @ W  (MFMA; B-frags direct from prepacked global W^T) -> xs_t
//     stored TRANSPOSED in LDS: xs[c4 * 72 + node].
//  2: logits: wave = head, lane = node; conflict-free column reads.
//  3: 9-edge softmax (8 edges + self-loop) -> dense per-head P[64x64] bf16
//     (pairwise dedupe of repeated edges; idempotent stores).
//  4: out = 0.25 * sum_h P_h @ X_h + bias (+ELU) via MFMA, write global bf16.
// ---------------------------------------------------------------------------
template<int KDIM, int KP, int C, bool ELU, typename AT>
__global__ __launch_bounds__(256)
void gat_layer(const AT* __restrict__ A, const bf16* __restrict__ Wt,
               const int* __restrict__ esrc,
               const float* __restrict__ a_src, const float* __restrict__ a_dst,
               const float* __restrict__ bias, bf16* __restrict__ out) {
  constexpr int C4  = NHEADS * C;          // 400 / 512
  constexpr int NCH = (C4 + 63) / 64;      // 7 / 8
  constexpr int C4P = NCH * 64;            // 448 / 512
  constexpr int NT  = (C + 15) / 16;       // 7 / 8
  constexpr int LDA = KP + 8;              // 104 / 136
  constexpr int LDT = 72;                  // xs_t row stride (shorts)
  constexpr int LDP = 72;                  // P row stride (shorts)

  __shared__ __align__(16) short          As[64 * LDA];
  __shared__ __align__(16) unsigned short xs[C4P * LDT];     // xl^T slab
  __shared__ __align__(16) short          Ps[NHEADS * 64 * LDP];
  __shared__ float avs[C4], avd[C4], bia[C];
  __shared__ int   edg[K_NODES * DEG];
  __shared__ float als[64 * 5], ald[64 * 5];                 // pad 5: bank spread

  const int g = blockIdx.x;
  const int t = threadIdx.x;

  // ---- phase 0 ----
  if constexpr (sizeof(AT) == 4) {
    constexpr int QR = KDIM / 4;           // layer 1: f32 input, K%4==0
    for (int idx = t; idx < 64 * QR; idx += 256) {
      int m = idx / QR, q = idx - m * QR;
      const float4 v = *(const float4*)((const float*)A +
                                        ((size_t)(g * 64 + m) * KDIM + q * 4));
      short* d = &As[m * LDA + q * 4];
      d[0] = f2bf_s(v.x); d[1] = f2bf_s(v.y); d[2] = f2bf_s(v.z); d[3] = f2bf_s(v.w);
    }
  } else {
    constexpr int PR = KDIM / 2;           // layer 2: bf16 input, K even
    for (int idx = t; idx < 64 * PR; idx += 256) {
      int m = idx / PR, p = idx - m * PR;
      const ushort2 v = *(const ushort2*)((const unsigned short*)A +
                                          ((size_t)(g * 64 + m) * KDIM + p * 2));
      As[m * LDA + p * 2]     = (short)v.x;
      As[m * LDA + p * 2 + 1] = (short)v.y;
    }
  }
  if constexpr (KP > KDIM) {
    constexpr int TR = KP - KDIM;
    for (int idx = t; idx < 64 * TR; idx += 256) {
      int m = idx / TR, kk = idx - m * TR;
      As[m * LDA + KDIM + kk] = 0;
    }
  }
  for (int idx = t; idx < C4; idx += 256) { avs[idx] = a_src[idx]; avd[idx] = a_dst[idx]; }
  for (int idx = t; idx < C;  idx += 256) bia[idx] = bias[idx];
  for (int idx = t; idx < K_NODES * DEG; idx += 256)
    edg[idx] = esrc[g * K_NODES * DEG + idx] & (K_NODES - 1);
  // zero P (us8 stores)
  for (int idx = t; idx < NHEADS * 64 * LDP / 8; idx += 256)
    *(us8*)&Ps[idx * 8] = (us8)0;
  __syncthreads();

  const int wv = t >> 6;
  const int l  = t & 63;
  const int lm = l & 15;
  const int lk = (l >> 4) * 8;
  const int rq = (l >> 4) * 4;

  // ---- phase 1: per-wave column chunks, B-frags direct from global W^T ----
  for (int ch = wv; ch < NCH; ch += 4) {
    const int n0 = ch * 64;
    frag_cd acc[4][4] = {};
#pragma unroll
    for (int ks = 0; ks < KP; ks += 32) {
      frag_ab b[4];
#pragma unroll
      for (int nt = 0; nt < 4; ++nt)
        b[nt] = *(const frag_ab*)((const short*)Wt +
                                  (size_t)(n0 + nt * 16 + lm) * KP + ks + lk);
#pragma unroll
      for (int mt = 0; mt < 4; ++mt) {
        frag_ab a = *(const frag_ab*)&As[(mt * 16 + lm) * LDA + ks + lk];
#pragma unroll
        for (int nt = 0; nt < 4; ++nt)
          acc[mt][nt] = __builtin_amdgcn_mfma_f32_16x16x32_bf16(a, b[nt],
                                                                acc[mt][nt], 0, 0, 0);
      }
    }
    // write xs transposed: C-frag col(lane&15) -> c4 row; rows rq..rq+3 -> nodes
#pragma unroll
    for (int mt = 0; mt < 4; ++mt) {
#pragma unroll
      for (int nt = 0; nt < 4; ++nt) {
        const int c4 = n0 + nt * 16 + lm;
        us4 o;
#pragma unroll
        for (int r = 0; r < 4; ++r) o[r] = (unsigned short)f2bf_s(acc[mt][nt][r]);
        *(us4*)&xs[c4 * LDT + mt * 16 + rq] = o;
      }
    }
  }
  __syncthreads();

  // ---- phase 2: logits. wave = head, lane = node; stride-2B reads (free) ----
  {
    const int h = wv, n = l;
    float ss = 0.f, sd = 0.f;
#pragma unroll 4
    for (int c = 0; c < C; ++c) {
      const float v = us2f(xs[(h * C + c) * LDT + n]);
      ss += v * avs[h * C + c];
      sd += v * avd[h * C + c];
    }
    als[n * 5 + h] = ss;
    ald[n * 5 + h] = sd;
  }
  __syncthreads();

  // ---- phase 3: softmax -> dense P (thread = (node, head)) ----
  {
    const int n = t >> 2, h = t & 3;
    const float ad = ald[n * 5 + h];
    int   sv[9];
    float a[9];
#pragma unroll
    for (int j = 0; j < 8; ++j) sv[j] = edg[n * DEG + j];
    sv[8] = n;
#pragma unroll
    for (int j = 0; j < 9; ++j) {
      float v = als[sv[j] * 5 + h] + ad;
      a[j] = (v >= 0.f) ? v : 0.2f * v;       // leaky_relu 0.2
    }
    float m = -1e30f;
#pragma unroll
    for (int j = 0; j < 9; ++j) m = fmaxf(m, a[j]);
    float s = 0.f;
#pragma unroll
    for (int j = 0; j < 9; ++j) { a[j] = __expf(a[j] - m); s += a[j]; }
    const float inv = 1.f / (s + 1e-16f);
    // dedupe duplicated sources: store total weight per target (idempotent)
    short* prow = &Ps[(h * 64 + n) * LDP];
#pragma unroll
    for (int j = 0; j < 9; ++j) {
      float tw = a[j];
#pragma unroll
      for (int i = 0; i < 9; ++i)
        if (i != j && sv[i] == sv[j]) tw += a[i];
      prow[sv[j]] = f2bf_s(tw * inv);
    }
  }
  __syncthreads();

  // ---- phase 4: out = 0.25 * sum_h P_h @ X_h + bias (+ELU), MFMA ----
  {
    const int mw = wv * 16;                  // wave's 16 dst nodes
    frag_cd acc[NT] = {};
#pragma unroll
    for (int h = 0; h < NHEADS; ++h) {
#pragma unroll
      for (int ks = 0; ks < 64; ks += 32) {
        frag_ab a = *(const frag_ab*)&Ps[(h * 64 + mw + lm) * LDP + ks + lk];
#pragma unroll
        for (int nt = 0; nt < NT; ++nt) {
          frag_ab b = *(const frag_ab*)&xs[(h * C + nt * 16 + lm) * LDT + ks + lk];
          acc[nt] = __builtin_amdgcn_mfma_f32_16x16x32_bf16(a, b, acc[nt], 0, 0, 0);
        }
      }
    }
    unsigned short* outp = (unsigned short*)out + (size_t)(g * 64) * C;
#pragma unroll
    for (int nt = 0; nt < NT; ++nt) {
      const int c = nt * 16 + lm;
      if (c < C) {
        const float bc = bia[c];
#pragma unroll
        for (int r = 0; r < 4; ++r) {
          float vv = acc[nt][r] * 0.25f + bc;
          if (ELU) vv = (vv > 0.f) ? vv : (__expf(vv) - 1.f);
          outp[(size_t)(mw + rq + r) * C + c] = (unsigned short)f2bf_s(vv);
        }
      }
    }
  }
}

// ---------------------------------------------------------------------------
// MFMA MLP head (verified R8). Grid 256 = (k) x (ms): block handles rows
// b in [ms*64, ms*64+64) of xg[k] = h2[b*64+k, :].
// ---------------------------------------------------------------------------
__global__ __launch_bounds__(256)
void mlp_mfma(const bf16* __restrict__ h2,
              const float* __restrict__ fw1, const float* __restrict__ fb1,
              const float* __restrict__ fw2, const float* __restrict__ fb2,
              float* __restrict__ pred) {
  constexpr int LDA = C2 + 8;
  constexpr int LDH = HID + 8;
  __shared__ __align__(16) short As[64 * LDA];
  __shared__ __align__(16) short B1[HID * LDA];
  __shared__ __align__(16) short Hs[64 * LDH];
  __shared__ __align__(16) short B2[32 * LDH];
  __shared__ float b1s[HID];
  __shared__ float b2s[32];

  const int k  = blockIdx.x & 63;
  const int ms = blockIdx.x >> 6;
  const int t  = threadIdx.x;

  for (int idx = t; idx < 64 * 16; idx += 256) {
    int r = idx >> 4, o = idx & 15;
    const us8 v = *(const us8*)((const unsigned short*)h2 +
        ((size_t)((ms * 64 + r) * K_NODES + k) * C2) + o * 8);
    *(us8*)&As[r * LDA + o * 8] = v;
  }
  for (int idx = t; idx < C2 * HID; idx += 256) {
    int kk = idx >> 6, n = idx & 63;
    B1[n * LDA + kk] = f2bf_s(fw1[(size_t)k * C2 * HID + kk * HID + n]);
  }
  for (int idx = t; idx < HID * 32; idx += 256) {
    int kk = idx >> 5, n = idx & 31;
    float v = (n < OUT_SZ) ? fw2[(size_t)k * HID * OUT_SZ + kk * OUT_SZ + n] : 0.f;
    B2[n * LDH + kk] = f2bf_s(v);
  }
  if (t < HID) b1s[t] = fb1[k * HID + t];
  if (t < 32)  b2s[t] = (t < OUT_SZ) ? fb2[k * OUT_SZ + t] : 0.f;
  __syncthreads();

  const int wv = t >> 6;
  const int l  = t & 63;
  const int lm = l & 15;
  const int lk = (l >> 4) * 8;
  const int rq = (l >> 4) * 4;

  frag_cd acc[4] = {};
#pragma unroll
  for (int ks = 0; ks < C2; ks += 32) {
    frag_ab a = *(const frag_ab*)&As[(wv * 16 + lm) * LDA + ks + lk];
#pragma unroll
    for (int nt = 0; nt < 4; ++nt) {
      frag_ab b = *(const frag_ab*)&B1[(nt * 16 + lm) * LDA + ks + lk];
      acc[nt] = __builtin_amdgcn_mfma_f32_16x16x32_bf16(a, b, acc[nt], 0, 0, 0);
    }
  }
#pragma unroll
  for (int nt = 0; nt < 4; ++nt) {
    const int j  = nt * 16 + lm;
    const float bj = b1s[j];
#pragma unroll
    for (int r = 0; r < 4; ++r) {
      const int m = wv * 16 + rq + r;
      Hs[m * LDH + j] = f2bf_s(fmaxf(acc[nt][r] + bj, 0.f));
    }
  }
  __syncthreads();

  frag_cd acc2[2] = {};
#pragma unroll
  for (int ks = 0; ks < HID; ks += 32) {
    frag_ab a = *(const frag_ab*)&Hs[(wv * 16 + lm) * LDH + ks + lk];
#pragma unroll
    for (int nt = 0; nt < 2; ++nt) {
      frag_ab b = *(const frag_ab*)&B2[(nt * 16 + lm) * LDH + ks + lk];
      acc2[nt] = __builtin_amdgcn_mfma_f32_16x16x32_bf16(a, b, acc2[nt], 0, 0, 0);
    }
  }
#pragma unroll
  for (int nt = 0; nt < 2; ++nt) {
    const int q = nt * 16 + lm;
    if (q < OUT_SZ) {
      const float bq = b2s[q];
#pragma unroll
      for (int r = 0; r < 4; ++r) {
        const int m = wv * 16 + rq + r;
        pred[((size_t)k * B_GRAPHS + ms * 64 + m) * OUT_SZ + q] = acc2[nt][r] + bq;
      }
    }
  }
}

// ---------------------------------------------------------------------------
// yg = float(bf16(y)) in identical flat order (matches bf16-cast np reference).
// ---------------------------------------------------------------------------
__global__ __launch_bounds__(256)
void yg_kernel(const float* __restrict__ y, float* __restrict__ dst) {
  int i = (blockIdx.x * 256 + threadIdx.x) * 4;
  float4 v = *(const float4*)(y + i);
  v.x = __bfloat162float(__float2bfloat16(v.x));
  v.y = __bfloat162float(__float2bfloat16(v.y));
  v.z = __bfloat162float(__float2bfloat16(v.z));
  v.w = __bfloat162float(__float2bfloat16(v.w));
  *(float4*)(dst + i) = v;
}

// ---------------------------------------------------------------------------
extern "C" void kernel_launch(void* const* d_in, const int* in_sizes, int n_in,
                              void* d_out, int out_size, void* d_ws, size_t ws_size,
                              hipStream_t stream) {
  const float* x   = (const float*)d_in[0];
  const int*   ei  = (const int*)d_in[1];    // [2,E]: first E entries = src
  const float* y   = (const float*)d_in[3];
  const float* W1  = (const float*)d_in[4];
  const float* as1 = (const float*)d_in[5];
  const float* ad1 = (const float*)d_in[6];
  const float* b1  = (const float*)d_in[7];
  const float* W2  = (const float*)d_in[8];
  const float* as2 = (const float*)d_in[9];
  const float* ad2 = (const float*)d_in[10];
  const float* b2  = (const float*)d_in[11];
  const float* fw1 = (const float*)d_in[12];
  const float* fb1 = (const float*)d_in[13];
  const float* fw2 = (const float*)d_in[14];
  const float* fb2 = (const float*)d_in[15];

  // Workspace: h1, h2, W1t, W2t  (~7.7 MB)
  bf16* h1  = (bf16*)d_ws;
  bf16* h2  = h1 + (size_t)N_NODES * C1;
  bf16* W1t = h2 + (size_t)N_NODES * C2;
  bf16* W2t = W1t + W1T_ROWS * W1T_K;

  float* out = (float*)d_out;

  // ---- prepack W^T (bf16, padded) ----
  const int pack_elems = W1T_ROWS * W1T_K + W2T_ROWS * W2T_K;
  pack_w<<<(pack_elems + 255) / 256, 256, 0, stream>>>(W1, W2, W1t, W2t);

  // ---- fused GAT layers ----
  gat_layer<IN_F, IN_F, C1, true, float>
      <<<B_GRAPHS, 256, 0, stream>>>(x, W1t, ei, as1, ad1, b1, h1);
  gat_layer<C1, 128, C2, false, unsigned short>
      <<<B_GRAPHS, 256, 0, stream>>>((const unsigned short*)h1, W2t, ei,
                                     as2, ad2, b2, h2);

  // ---- MFMA MLP head -> pred (chunk0, f32) ----
  mlp_mfma<<<K_NODES * 4, 256, 0, stream>>>(h2, fw1, fb1, fw2, fb2, out);

  // ---- yg -> chunk1 ----
  yg_kernel<<<PRED_ELEMS / 4 / 256, 256, 0, stream>>>(y, out + PRED_ELEMS);
}

// Round 11
// 118.631 us; speedup vs baseline: 3.0069x; 1.0742x over previous
//
#include <hip/hip_runtime.h>
#include <hip/hip_bf16.h>
#include <math.h>

// Dtype model (pinned R0-R4): float inputs f32; edge_index int32; d_out read
// as f32: chunk0 = pred f32[0:393216], chunk1 = yg f32[393216:786432]; np
// reference computed from bf16-cast inputs -> bf16 intermediates safe.
//
// R7: register spills kill. R9: strided us8 LDS reads = bank-conflict storm.
// R10: P[64x64]@X MFMA aggregation + transposed xs + prepacked W^T -> 127us.
// R11 (this): fuse BOTH GAT layers into one per-graph kernel @ 512 threads
// (2 waves/SIMD), h1 stays in LDS (L1 aggregation writes the L2 A-slab
// directly), P support identical across layers (same edges) so no re-zero.
// pack_w + yg merged into one prep kernel. 5 launches -> 3.

#define N_NODES 16384
#define B_GRAPHS 256
#define K_NODES 64
#define DEG 8
#define NHEADS 4
#define C1 100
#define C2 128
#define IN_F 96
#define HID 64
#define OUT_SZ 24
#define PRED_ELEMS (K_NODES * B_GRAPHS * OUT_SZ)   // 393216

#define W1T_ROWS 448   // 400 cols padded to 7*64
#define W1T_K    96
#define W2T_ROWS 512
#define W2T_K    128   // 100 padded

using bf16 = __hip_bfloat16;
typedef __attribute__((ext_vector_type(8))) short          frag_ab;  // 8 bf16
typedef __attribute__((ext_vector_type(4))) float          frag_cd;  // 4 f32
typedef unsigned short us8 __attribute__((ext_vector_type(8)));      // 16 B
typedef unsigned short us4 __attribute__((ext_vector_type(4)));      // 8 B

__device__ __forceinline__ float us2f(unsigned short u) {
  return __bfloat162float(__ushort_as_bfloat16(u));
}
__device__ __forceinline__ short f2bf_s(float f) {
  return __builtin_bit_cast(short, __float2bfloat16(f));
}

// ---------------------------------------------------------------------------
// prep: pack W1^T/W2^T (bf16, padded, k-contiguous) + yg = float(bf16(y)).
// All three jobs independent of everything else -> one kernel, one launch.
// ---------------------------------------------------------------------------
#define P1N (W1T_ROWS * W1T_K)    // 43008
#define P2N (W2T_ROWS * W2T_K)    // 65536
#define YG4 (PRED_ELEMS / 4)      // 98304

__global__ __launch_bounds__(256)
void prep(const float* __restrict__ W1, const float* __restrict__ W2,
          const float* __restrict__ y,
          bf16* __restrict__ W1t, bf16* __restrict__ W2t,
          float* __restrict__ yg) {
  int idx = blockIdx.x * 256 + threadIdx.x;
  if (idx < P1N) {
    int c = idx / W1T_K, k = idx - c * W1T_K;
    W1t[idx] = __float2bfloat16((c < 400) ? W1[(size_t)k * 400 + c] : 0.f);
  } else if (idx < P1N + P2N) {
    int i2 = idx - P1N;
    int c = i2 >> 7, k = i2 & 127;
    W2t[i2] = __float2bfloat16((k < 100) ? W2[(size_t)k * 512 + c] : 0.f);
  } else {
    int j = idx - P1N - P2N;
    if (j < YG4) {
      int i = j * 4;
      float4 v = *(const float4*)(y + i);
      v.x = __bfloat162float(__float2bfloat16(v.x));
      v.y = __bfloat162float(__float2bfloat16(v.y));
      v.z = __bfloat162float(__float2bfloat16(v.z));
      v.w = __bfloat162float(__float2bfloat16(v.w));
      *(float4*)(yg + i) = v;
    }
  }
}

// ---------------------------------------------------------------------------
// Fused two-layer GAT, one block per graph (grid=256), 512 threads (8 waves).
// LDS (~141 KB): As (A-slab, both layers), xs (xl^T), Ps (4 dense P), params.
// L1: stage x -> As(stride 104); xl1 = As@W1t -> xs^T; logits; softmax -> Ps;
//     agg MFMA -> h1 written into As(stride 136, pads zeroed by spare waves).
// L2: xl2 = As@W2t -> xs^T; logits; softmax -> Ps (same support, no re-zero);
//     agg MFMA -> h2 global (bf16).
// ---------------------------------------------------------------------------
__global__ __launch_bounds__(512)
void gat_fused(const float* __restrict__ x,
               const bf16* __restrict__ W1t, const bf16* __restrict__ W2t,
               const int* __restrict__ esrc,
               const float* __restrict__ as1, const float* __restrict__ ad1,
               const float* __restrict__ b1,
               const float* __restrict__ as2, const float* __restrict__ ad2,
               const float* __restrict__ b2,
               bf16* __restrict__ h2out) {
  constexpr int LDA1 = IN_F + 8;     // 104 (shorts)
  constexpr int LDA2 = 136;          // layer-2 A stride (K=128 + 8)
  constexpr int LDT  = 72;           // xs/Ps row stride (shorts)

  __shared__ __align__(16) short          As[64 * LDA2];          // 17.4 KB
  __shared__ __align__(16) unsigned short xs[512 * LDT];          // 73.7 KB
  __shared__ __align__(16) short          Ps[NHEADS * 64 * LDT];  // 36.9 KB
  __shared__ float avs1[400], avd1[400], avs2[512], avd2[512];
  __shared__ float bia1[C1], bia2[C2];
  __shared__ int   edg[K_NODES * DEG];
  __shared__ float als[64 * 5], ald[64 * 5];

  const int g = blockIdx.x;
  const int t = threadIdx.x;
  const int wv = t >> 6;
  const int l  = t & 63;
  const int lm = l & 15;
  const int lk = (l >> 4) * 8;
  const int rq = (l >> 4) * 4;

  // ================= phase 0: stage =================
  {
    constexpr int QR = IN_F / 4;     // 24 float4 per row
    for (int idx = t; idx < 64 * QR; idx += 512) {
      int m = idx / QR, q = idx - m * QR;
      const float4 v = *(const float4*)(x + ((size_t)(g * 64 + m) * IN_F + q * 4));
      short* d = &As[m * LDA1 + q * 4];
      d[0] = f2bf_s(v.x); d[1] = f2bf_s(v.y); d[2] = f2bf_s(v.z); d[3] = f2bf_s(v.w);
    }
  }
  for (int idx = t; idx < 400; idx += 512) { avs1[idx] = as1[idx]; avd1[idx] = ad1[idx]; }
  for (int idx = t; idx < 512; idx += 512) { avs2[idx] = as2[idx]; avd2[idx] = ad2[idx]; }
  if (t < C1) bia1[t] = b1[t];
  if (t < C2) bia2[t] = b2[t];
  if (t < K_NODES * DEG) edg[t] = esrc[g * K_NODES * DEG + t] & (K_NODES - 1);
  for (int idx = t; idx < NHEADS * 64 * LDT / 8; idx += 512)
    *(us8*)&Ps[idx * 8] = (us8)0;
  __syncthreads();

  // ================= L1 phase 1: xl1 = As @ W1t -> xs^T =================
  if (wv < 7) {
    const int n0 = wv * 64;
    frag_cd acc[4][4] = {};
#pragma unroll
    for (int ks = 0; ks < IN_F; ks += 32) {
      frag_ab b[4];
#pragma unroll
      for (int nt = 0; nt < 4; ++nt)
        b[nt] = *(const frag_ab*)((const short*)W1t +
                                  (size_t)(n0 + nt * 16 + lm) * W1T_K + ks + lk);
#pragma unroll
      for (int mt = 0; mt < 4; ++mt) {
        frag_ab a = *(const frag_ab*)&As[(mt * 16 + lm) * LDA1 + ks + lk];
#pragma unroll
        for (int nt = 0; nt < 4; ++nt)
          acc[mt][nt] = __builtin_amdgcn_mfma_f32_16x16x32_bf16(a, b[nt],
                                                                acc[mt][nt], 0, 0, 0);
      }
    }
#pragma unroll
    for (int mt = 0; mt < 4; ++mt)
#pragma unroll
      for (int nt = 0; nt < 4; ++nt) {
        const int c4 = n0 + nt * 16 + lm;
        us4 o;
#pragma unroll
        for (int r = 0; r < 4; ++r) o[r] = (unsigned short)f2bf_s(acc[mt][nt][r]);
        *(us4*)&xs[c4 * LDT + mt * 16 + rq] = o;
      }
  }
  __syncthreads();

  // ================= L1 phase 2: logits =================
  if (t < 256) {
    const int n = t >> 2, h = t & 3;
    float ss = 0.f, sd = 0.f;
#pragma unroll 4
    for (int c = 0; c < C1; ++c) {
      const float v = us2f(xs[(h * C1 + c) * LDT + n]);
      ss += v * avs1[h * C1 + c];
      sd += v * avd1[h * C1 + c];
    }
    als[n * 5 + h] = ss;
    ald[n * 5 + h] = sd;
  }
  __syncthreads();

  // ====== L1 phase 3: softmax -> Ps; spare threads zero As2 k-pads ======
  if (t < 256) {
    const int n = t >> 2, h = t & 3;
    const float ad = ald[n * 5 + h];
    int   sv[9];
    float a[9];
#pragma unroll
    for (int j = 0; j < 8; ++j) sv[j] = edg[n * DEG + j];
    sv[8] = n;
#pragma unroll
    for (int j = 0; j < 9; ++j) {
      float v = als[sv[j] * 5 + h] + ad;
      a[j] = (v >= 0.f) ? v : 0.2f * v;       // leaky_relu 0.2
    }
    float m = -1e30f;
#pragma unroll
    for (int j = 0; j < 9; ++j) m = fmaxf(m, a[j]);
    float s = 0.f;
#pragma unroll
    for (int j = 0; j < 9; ++j) { a[j] = __expf(a[j] - m); s += a[j]; }
    const float inv = 1.f / (s + 1e-16f);
    short* prow = &Ps[(h * 64 + n) * LDT];
#pragma unroll
    for (int j = 0; j < 9; ++j) {
      float tw = a[j];
#pragma unroll
      for (int i = 0; i < 9; ++i)
        if (i != j && sv[i] == sv[j]) tw += a[i];
      prow[sv[j]] = f2bf_s(tw * inv);         // idempotent dedupe
    }
  } else {
    // zero As layer-2 k-padding (k = 100..127), As1 is dead here
    for (int i = t - 256; i < 64 * 28; i += 256) {
      int m = i / 28, kk = 100 + (i - m * 28);
      As[m * LDA2 + kk] = 0;
    }
  }
  __syncthreads();

  // ====== L1 phase 4: h1 = 0.25*sum_h P_h @ X_h + bias, ELU -> As2 ======
  {
    const int mw = (wv & 3) * 16;
    const int cg = wv >> 2;
    const int ntb = cg * 4;
    const int nte = (cg == 0) ? 4 : 7;        // NT=7 tiles split 4+3
    frag_cd acc[4] = {};
#pragma unroll
    for (int h = 0; h < NHEADS; ++h)
#pragma unroll
      for (int ks = 0; ks < 64; ks += 32) {
        frag_ab a = *(const frag_ab*)&Ps[(h * 64 + mw + lm) * LDT + ks + lk];
        for (int nt = ntb; nt < nte; ++nt) {
          frag_ab b = *(const frag_ab*)&xs[(h * C1 + nt * 16 + lm) * LDT + ks + lk];
          acc[nt - ntb] = __builtin_amdgcn_mfma_f32_16x16x32_bf16(a, b,
                                                                  acc[nt - ntb], 0, 0, 0);
      }
    }
    for (int nt = ntb; nt < nte; ++nt) {
      const int c = nt * 16 + lm;
      if (c < C1) {
        const float bc = bia1[c];
#pragma unroll
        for (int r = 0; r < 4; ++r) {
          float vv = acc[nt - ntb][r] * 0.25f + bc;
          vv = (vv > 0.f) ? vv : (__expf(vv) - 1.f);   // ELU
          As[(mw + rq + r) * LDA2 + c] = f2bf_s(vv);
        }
      }
    }
  }
  __syncthreads();

  // ================= L2 phase 1: xl2 = As @ W2t -> xs^T =================
  {
    const int n0 = wv * 64;
    frag_cd acc[4][4] = {};
#pragma unroll
    for (int ks = 0; ks < 128; ks += 32) {
      frag_ab b[4];
#pragma unroll
      for (int nt = 0; nt < 4; ++nt)
        b[nt] = *(const frag_ab*)((const short*)W2t +
                                  (size_t)(n0 + nt * 16 + lm) * W2T_K + ks + lk);
#pragma unroll
      for (int mt = 0; mt < 4; ++mt) {
        frag_ab a = *(const frag_ab*)&As[(mt * 16 + lm) * LDA2 + ks + lk];
#pragma unroll
        for (int nt = 0; nt < 4; ++nt)
          acc[mt][nt] = __builtin_amdgcn_mfma_f32_16x16x32_bf16(a, b[nt],
                                                                acc[mt][nt], 0, 0, 0);
      }
    }
#pragma unroll
    for (int mt = 0; mt < 4; ++mt)
#pragma unroll
      for (int nt = 0; nt < 4; ++nt) {
        const int c4 = n0 + nt * 16 + lm;
        us4 o;
#pragma unroll
        for (int r = 0; r < 4; ++r) o[r] = (unsigned short)f2bf_s(acc[mt][nt][r]);
        *(us4*)&xs[c4 * LDT + mt * 16 + rq] = o;
      }
  }
  __syncthreads();

  // ================= L2 phase 2: logits =================
  if (t < 256) {
    const int n = t >> 2, h = t & 3;
    float ss = 0.f, sd = 0.f;
#pragma unroll 4
    for (int c = 0; c < C2; ++c) {
      const float v = us2f(xs[(h * C2 + c) * LDT + n]);
      ss += v * avs2[h * C2 + c];
      sd += v * avd2[h * C2 + c];
    }
    als[n * 5 + h] = ss;
    ald[n * 5 + h] = sd;
  }
  __syncthreads();

  // ====== L2 phase 3: softmax -> Ps (same nonzero support; no re-zero) ======
  if (t < 256) {
    const int n = t >> 2, h = t & 3;
    const float ad = ald[n * 5 + h];
    int   sv[9];
    float a[9];
#pragma unroll
    for (int j = 0; j < 8; ++j) sv[j] = edg[n * DEG + j];
    sv[8] = n;
#pragma unroll
    for (int j = 0; j < 9; ++j) {
      float v = als[sv[j] * 5 + h] + ad;
      a[j] = (v >= 0.f) ? v : 0.2f * v;
    }
    float m = -1e30f;
#pragma unroll
    for (int j = 0; j < 9; ++j) m = fmaxf(m, a[j]);
    float s = 0.f;
#pragma unroll
    for (int j = 0; j < 9; ++j) { a[j] = __expf(a[j] - m); s += a[j]; }
    const float inv = 1.f / (s + 1e-16f);
    short* prow = &Ps[(h * 64 + n) * LDT];
#pragma unroll
    for (int j = 0; j < 9; ++j) {
      float tw = a[j];
#pragma unroll
      for (int i = 0; i < 9; ++i)
        if (i != j && sv[i] == sv[j]) tw += a[i];
      prow[sv[j]] = f2bf_s(tw * inv);
    }
  }
  __syncthreads();

  // ====== L2 phase 4: h2 = 0.25*sum_h P_h @ X_h + bias -> global ======
  {
    const int mw = (wv & 3) * 16;
    const int cg = wv >> 2;
    const int ntb = cg * 4;                    // NT=8 split 4+4
    frag_cd acc[4] = {};
#pragma unroll
    for (int h = 0; h < NHEADS; ++h)
#pragma unroll
      for (int ks = 0; ks < 64; ks += 32) {
        frag_ab a = *(const frag_ab*)&Ps[(h * 64 + mw + lm) * LDT + ks + lk];
#pragma unroll
        for (int nt = 0; nt < 4; ++nt) {
          frag_ab b = *(const frag_ab*)&xs[(h * C2 + (ntb + nt) * 16 + lm) * LDT + ks + lk];
          acc[nt] = __builtin_amdgcn_mfma_f32_16x16x32_bf16(a, b, acc[nt], 0, 0, 0);
        }
      }
    unsigned short* outp = (unsigned short*)h2out + (size_t)(g * 64) * C2;
#pragma unroll
    for (int nt = 0; nt < 4; ++nt) {
      const int c = (ntb + nt) * 16 + lm;
      const float bc = bia2[c];
#pragma unroll
      for (int r = 0; r < 4; ++r) {
        float vv = acc[nt][r] * 0.25f + bc;
        outp[(size_t)(mw + rq + r) * C2 + c] = (unsigned short)f2bf_s(vv);
      }
    }
  }
}

// ---------------------------------------------------------------------------
// MFMA MLP head (verified R8/R10). Grid 256 = (k) x (ms).
// ---------------------------------------------------------------------------
__global__ __launch_bounds__(256)
void mlp_mfma(const bf16* __restrict__ h2,
              const float* __restrict__ fw1, const float* __restrict__ fb1,
              const float* __restrict__ fw2, const float* __restrict__ fb2,
              float* __restrict__ pred) {
  constexpr int LDA = C2 + 8;
  constexpr int LDH = HID + 8;
  __shared__ __align__(16) short As[64 * LDA];
  __shared__ __align__(16) short B1[HID * LDA];
  __shared__ __align__(16) short Hs[64 * LDH];
  __shared__ __align__(16) short B2[32 * LDH];
  __shared__ float b1s[HID];
  __shared__ float b2s[32];

  const int k  = blockIdx.x & 63;
  const int ms = blockIdx.x >> 6;
  const int t  = threadIdx.x;

  for (int idx = t; idx < 64 * 16; idx += 256) {
    int r = idx >> 4, o = idx & 15;
    const us8 v = *(const us8*)((const unsigned short*)h2 +
        ((size_t)((ms * 64 + r) * K_NODES + k) * C2) + o * 8);
    *(us8*)&As[r * LDA + o * 8] = v;
  }
  for (int idx = t; idx < C2 * HID; idx += 256) {
    int kk = idx >> 6, n = idx & 63;
    B1[n * LDA + kk] = f2bf_s(fw1[(size_t)k * C2 * HID + kk * HID + n]);
  }
  for (int idx = t; idx < HID * 32; idx += 256) {
    int kk = idx >> 5, n = idx & 31;
    float v = (n < OUT_SZ) ? fw2[(size_t)k * HID * OUT_SZ + kk * OUT_SZ + n] : 0.f;
    B2[n * LDH + kk] = f2bf_s(v);
  }
  if (t < HID) b1s[t] = fb1[k * HID + t];
  if (t < 32)  b2s[t] = (t < OUT_SZ) ? fb2[k * OUT_SZ + t] : 0.f;
  __syncthreads();

  const int wv = t >> 6;
  const int l  = t & 63;
  const int lm = l & 15;
  const int lk = (l >> 4) * 8;
  const int rq = (l >> 4) * 4;

  frag_cd acc[4] = {};
#pragma unroll
  for (int ks = 0; ks < C2; ks += 32) {
    frag_ab a = *(const frag_ab*)&As[(wv * 16 + lm) * LDA + ks + lk];
#pragma unroll
    for (int nt = 0; nt < 4; ++nt) {
      frag_ab b = *(const frag_ab*)&B1[(nt * 16 + lm) * LDA + ks + lk];
      acc[nt] = __builtin_amdgcn_mfma_f32_16x16x32_bf16(a, b, acc[nt], 0, 0, 0);
    }
  }
#pragma unroll
  for (int nt = 0; nt < 4; ++nt) {
    const int j  = nt * 16 + lm;
    const float bj = b1s[j];
#pragma unroll
    for (int r = 0; r < 4; ++r) {
      const int m = wv * 16 + rq + r;
      Hs[m * LDH + j] = f2bf_s(fmaxf(acc[nt][r] + bj, 0.f));
    }
  }
  __syncthreads();

  frag_cd acc2[2] = {};
#pragma unroll
  for (int ks = 0; ks < HID; ks += 32) {
    frag_ab a = *(const frag_ab*)&Hs[(wv * 16 + lm) * LDH + ks + lk];
#pragma unroll
    for (int nt = 0; nt < 2; ++nt) {
      frag_ab b = *(const frag_ab*)&B2[(nt * 16 + lm) * LDH + ks + lk];
      acc2[nt] = __builtin_amdgcn_mfma_f32_16x16x32_bf16(a, b, acc2[nt], 0, 0, 0);
    }
  }
#pragma unroll
  for (int nt = 0; nt < 2; ++nt) {
    const int q = nt * 16 + lm;
    if (q < OUT_SZ) {
      const float bq = b2s[q];
#pragma unroll
      for (int r = 0; r < 4; ++r) {
        const int m = wv * 16 + rq + r;
        pred[((size_t)k * B_GRAPHS + ms * 64 + m) * OUT_SZ + q] = acc2[nt][r] + bq;
      }
    }
  }
}

// ---------------------------------------------------------------------------
extern "C" void kernel_launch(void* const* d_in, const int* in_sizes, int n_in,
                              void* d_out, int out_size, void* d_ws, size_t ws_size,
                              hipStream_t stream) {
  const float* x   = (const float*)d_in[0];
  const int*   ei  = (const int*)d_in[1];    // [2,E]: first E entries = src
  const float* y   = (const float*)d_in[3];
  const float* W1  = (const float*)d_in[4];
  const float* as1 = (const float*)d_in[5];
  const float* ad1 = (const float*)d_in[6];
  const float* b1  = (const float*)d_in[7];
  const float* W2  = (const float*)d_in[8];
  const float* as2 = (const float*)d_in[9];
  const float* ad2 = (const float*)d_in[10];
  const float* b2  = (const float*)d_in[11];
  const float* fw1 = (const float*)d_in[12];
  const float* fb1 = (const float*)d_in[13];
  const float* fw2 = (const float*)d_in[14];
  const float* fb2 = (const float*)d_in[15];

  // Workspace: h2, W1t, W2t  (~4.4 MB)
  bf16* h2  = (bf16*)d_ws;
  bf16* W1t = h2 + (size_t)N_NODES * C2;
  bf16* W2t = W1t + P1N;

  float* out = (float*)d_out;

  // ---- prep: pack W^T + yg (all independent) ----
  prep<<<(P1N + P2N + YG4 + 255) / 256, 256, 0, stream>>>(
      W1, W2, y, W1t, W2t, out + PRED_ELEMS);

  // ---- fused two-layer GAT -> h2 ----
  gat_fused<<<B_GRAPHS, 512, 0, stream>>>(x, W1t, W2t, ei,
                                          as1, ad1, b1, as2, ad2, b2, h2);

  // ---- MFMA MLP head -> pred (chunk0, f32) ----
  mlp_mfma<<<K_NODES * 4, 256, 0, stream>>>(h2, fw1, fb1, fw2, fb2, out);
}